// Round 10
// baseline (449.660 us; speedup 1.0000x reference)
//
#include <hip/hip_runtime.h>
#include <hip/hip_bf16.h>
#include <math.h>

// Transformer block. Round 10: attention v3 — PV via 16x16x16 MFMA straight
// from the S^T C-fragment (no P LDS round-trip), register-prefetch K/V
// staging, exp2-folded softmax, 36KB LDS (4 blocks/CU). GEMMs as Round 9.
// D_MODEL=1024, N_HEAD=16, D_HEAD=64, EXP=4, B=2, T=2048, EPS=1e-5

#define D_MODEL 1024
#define N_HEAD  16
#define D_HEAD  64
#define SEQ_T   2048
#define BATCH   2
#define NROWS   (BATCH * SEQ_T)   // 4096
#define C3      (3 * D_MODEL)     // 3072
#define D_FF    (4 * D_MODEL)     // 4096

typedef __bf16 bf16x8 __attribute__((ext_vector_type(8)));
typedef __bf16 bf16x4t __attribute__((ext_vector_type(4)));
typedef short  s16x4  __attribute__((ext_vector_type(4)));
typedef float  f32x4  __attribute__((ext_vector_type(4)));

// s_waitcnt imm: vmcnt[3:0]=bits3:0, expcnt=bits6:4, lgkmcnt=bits11:8.
#define WAIT_VM6() __builtin_amdgcn_s_waitcnt(0x0F76)
#define WAIT_VM4() __builtin_amdgcn_s_waitcnt(0x0F74)
#define WAIT_VM0() __builtin_amdgcn_s_waitcnt(0x0F70)

// 16x16x16 bf16 MFMA: builtin name differs across ROCm versions.
__device__ __forceinline__ f32x4 mfma16_bf16(s16x4 a, s16x4 b, f32x4 c)
{
#if __has_builtin(__builtin_amdgcn_mfma_f32_16x16x16_bf16)
    return __builtin_amdgcn_mfma_f32_16x16x16_bf16(
        __builtin_bit_cast(bf16x4t, a), __builtin_bit_cast(bf16x4t, b), c, 0, 0, 0);
#else
    return __builtin_amdgcn_mfma_f32_16x16x16bf16_1k(a, b, c, 0, 0, 0);
#endif
}

// ---------------------------------------------------------------- LayerNorm
__global__ __launch_bounds__(256) void ln_kernel(
    const float* __restrict__ in, const float* __restrict__ w,
    const float* __restrict__ b, __hip_bfloat16* __restrict__ out, int D)
{
    const int row = blockIdx.x;
    const int tid = threadIdx.x;
    const float* x = in + (size_t)row * D;

    float s = 0.f, s2 = 0.f;
    for (int i = tid; i < D; i += 256) {
        float v = x[i];
        s += v; s2 += v * v;
    }
    __shared__ float rs[256], rs2[256];
    rs[tid] = s; rs2[tid] = s2;
    __syncthreads();
    for (int off = 128; off > 0; off >>= 1) {
        if (tid < off) { rs[tid] += rs[tid + off]; rs2[tid] += rs2[tid + off]; }
        __syncthreads();
    }
    const float mu   = rs[0] / D;
    const float var  = rs2[0] / D - mu * mu;
    const float rstd = rsqrtf(var + 1e-5f);

    __hip_bfloat16* o = out + (size_t)row * D;
    for (int i = tid; i < D; i += 256)
        o[i] = __float2bfloat16((x[i] - mu) * rstd * w[i] + b[i]);
}

// -------------------------------- merged weight transpose + bf16 cast (x4)
__global__ __launch_bounds__(256) void transpose_all_kernel(
    const float* __restrict__ attn_w, const float* __restrict__ proj_w,
    const float* __restrict__ fc_w,   const float* __restrict__ fc2_w,
    __hip_bfloat16* __restrict__ attn_wt, __hip_bfloat16* __restrict__ proj_wt,
    __hip_bfloat16* __restrict__ fc_wt,   __hip_bfloat16* __restrict__ fc2_wt)
{
    __shared__ float t[32][33];
    int tb = blockIdx.x;
    const float* W; __hip_bfloat16* Wt; int K, N;
    if (tb < 3072)      { W = attn_w; Wt = attn_wt; K = D_MODEL; N = C3; }
    else if (tb < 4096) { tb -= 3072; W = proj_w; Wt = proj_wt; K = D_MODEL; N = D_MODEL; }
    else if (tb < 8192) { tb -= 4096; W = fc_w;   Wt = fc_wt;   K = D_MODEL; N = D_FF; }
    else                { tb -= 8192; W = fc2_w;  Wt = fc2_wt;  K = D_FF;    N = D_MODEL; }
    const int ntx = N >> 5;
    const int k0 = (tb / ntx) * 32;
    const int n0 = (tb % ntx) * 32;

    const int tx = threadIdx.x & 31;
    const int ty = threadIdx.x >> 5;
#pragma unroll
    for (int i = 0; i < 4; ++i)
        t[ty + 8 * i][tx] = W[(size_t)(k0 + ty + 8 * i) * N + n0 + tx];
    __syncthreads();
#pragma unroll
    for (int i = 0; i < 4; ++i)
        Wt[(size_t)(n0 + ty + 8 * i) * K + k0 + tx] =
            __float2bfloat16(t[tx][ty + 8 * i]);
}

// ----------------------------------------------------------- helpers
__device__ __forceinline__ void async16(const __hip_bfloat16* g, __hip_bfloat16* l)
{
    __builtin_amdgcn_global_load_lds(
        (const __attribute__((address_space(1))) void*)g,
        (__attribute__((address_space(3))) void*)l, 16, 0, 0);
}

__device__ __forceinline__ float gelu_exact(float v)
{
    return 0.5f * v * (1.0f + erff(v * 0.70710678118654752f));
}

__device__ __forceinline__ void swizzle_bxy(int& bx, int& by)
{
    const int nbx = gridDim.x;
    const int lin = blockIdx.y * nbx + blockIdx.x;
    const int stripe = 4 * nbx;
    const int s = lin / stripe;
    const int rem = lin - s * stripe;
    by = s * 4 + (rem & 3);
    bx = rem >> 2;
}

// ---------------- Round-8 core: 128x128 block, 64x64 wave, 4-deep, vmcnt(4)
__device__ __forceinline__ void gemm_pipeline_core(
    const __hip_bfloat16* __restrict__ A,
    const __hip_bfloat16* __restrict__ Bt,
    int K, int row0, int col0,
    int wm, int wn, int ln15, int lq,
    f32x4 (&acc)[4][4])
{
    __shared__ __align__(16) __hip_bfloat16 As0[4096], As1[4096],
                                            As2[4096], As3[4096];
    __shared__ __align__(16) __hip_bfloat16 Bs0[4096], Bs1[4096],
                                            Bs2[4096], Bs3[4096];
    __hip_bfloat16* const Ab[4] = {As0, As1, As2, As3};
    __hip_bfloat16* const Bb[4] = {Bs0, Bs1, Bs2, Bs3};

    const int tid  = threadIdx.x;
    const int wv   = tid >> 6;
    const int lane = tid & 63;
    const int sr = wv * 16 + (lane >> 2);
    const int sq = (lane & 3) * 8;

    auto stage = [&](int kt, __hip_bfloat16* as, __hip_bfloat16* bs) {
        const int k0 = kt * 32;
#pragma unroll
        for (int i = 0; i < 2; ++i) {
            const int r = i * 64 + sr;
            async16(A  + (size_t)(row0 + r) * K + k0 + sq, as + r * 32);
            async16(Bt + (size_t)(col0 + r) * K + k0 + sq, bs + r * 32);
        }
    };

#pragma unroll
    for (int i = 0; i < 4; ++i)
#pragma unroll
        for (int j = 0; j < 4; ++j) acc[i][j] = (f32x4){0.f, 0.f, 0.f, 0.f};

    stage(0, Ab[0], Bb[0]);
    stage(1, Ab[1], Bb[1]);

    const int nt = K >> 5;
    for (int t0 = 0; t0 < nt; t0 += 4) {
#pragma unroll
        for (int u = 0; u < 4; ++u) {
            const int t = t0 + u;
            if (t + 1 < nt) WAIT_VM4(); else WAIT_VM0();
            __builtin_amdgcn_s_barrier();
            const __hip_bfloat16* as = Ab[u];
            const __hip_bfloat16* bs = Bb[u];
            bf16x8 af[4], bfr[4];
#pragma unroll
            for (int mi = 0; mi < 4; ++mi)
                af[mi] = *(const bf16x8*)&as[(wm + mi * 16 + ln15) * 32 + lq * 8];
#pragma unroll
            for (int ni = 0; ni < 4; ++ni)
                bfr[ni] = *(const bf16x8*)&bs[(wn + ni * 16 + ln15) * 32 + lq * 8];
#pragma unroll
            for (int mi = 0; mi < 4; ++mi)
#pragma unroll
                for (int ni = 0; ni < 4; ++ni)
                    acc[mi][ni] = __builtin_amdgcn_mfma_f32_16x16x32_bf16(
                        af[mi], bfr[ni], acc[mi][ni], 0, 0, 0);
            if (t + 2 < nt) stage(t + 2, Ab[(u + 2) & 3], Bb[(u + 2) & 3]);
        }
    }
}

// ---------------- Round-9 wide core: 256x128 block, 128x64 wave, 2-deep
__device__ __forceinline__ void gemm_pipeline_wide(
    const __hip_bfloat16* __restrict__ A,
    const __hip_bfloat16* __restrict__ Bt,
    int K, int row0, int col0,
    int wm, int wn, int ln15, int lq,
    f32x4 (&acc)[8][4])
{
    __shared__ __align__(16) __hip_bfloat16 As0[256 * 32], As1[256 * 32];
    __shared__ __align__(16) __hip_bfloat16 Bs0[128 * 32], Bs1[128 * 32];

    const int tid  = threadIdx.x;
    const int wv   = tid >> 6;
    const int lane = tid & 63;
    const int sr = wv * 16 + (lane >> 2);
    const int sq = (lane & 3) * 8;

    auto stage = [&](int kt, __hip_bfloat16* as, __hip_bfloat16* bs) {
        const int k0 = kt * 32;
#pragma unroll
        for (int i = 0; i < 4; ++i) {
            const int r = i * 64 + sr;
            async16(A + (size_t)(row0 + r) * K + k0 + sq, as + r * 32);
        }
#pragma unroll
        for (int i = 0; i < 2; ++i) {
            const int r = i * 64 + sr;
            async16(Bt + (size_t)(col0 + r) * K + k0 + sq, bs + r * 32);
        }
    };

#pragma unroll
    for (int i = 0; i < 8; ++i)
#pragma unroll
        for (int j = 0; j < 4; ++j) acc[i][j] = (f32x4){0.f, 0.f, 0.f, 0.f};

    stage(0, As0, Bs0);
    stage(1, As1, Bs1);

    const int nt = K >> 5;
    for (int t0 = 0; t0 < nt; t0 += 2) {
#pragma unroll
        for (int u = 0; u < 2; ++u) {
            const int t = t0 + u;
            if (t + 1 < nt) WAIT_VM6(); else WAIT_VM0();
            __builtin_amdgcn_s_barrier();
            const __hip_bfloat16* as = u ? As1 : As0;
            const __hip_bfloat16* bs = u ? Bs1 : Bs0;
            bf16x8 af[8], bfr[4];
#pragma unroll
            for (int mi = 0; mi < 8; ++mi)
                af[mi] = *(const bf16x8*)&as[(wm + mi * 16 + ln15) * 32 + lq * 8];
#pragma unroll
            for (int ni = 0; ni < 4; ++ni)
                bfr[ni] = *(const bf16x8*)&bs[(wn + ni * 16 + ln15) * 32 + lq * 8];
#pragma unroll
            for (int mi = 0; mi < 8; ++mi)
#pragma unroll
                for (int ni = 0; ni < 4; ++ni)
                    acc[mi][ni] = __builtin_amdgcn_mfma_f32_16x16x32_bf16(
                        af[mi], bfr[ni], acc[mi][ni], 0, 0, 0);
            __builtin_amdgcn_s_barrier();
            if (t + 2 < nt) stage(t + 2, u ? As1 : As0, u ? Bs1 : Bs0);
        }
    }
}

// ---------------- 128x128 kernel (proj, fc2)
__global__ __launch_bounds__(256) void mfma_gemm_kernel(
    const __hip_bfloat16* __restrict__ A,   // [M,K]
    const __hip_bfloat16* __restrict__ Bt,  // [N,K]
    const float* __restrict__ bias,         // [N]
    const float* __restrict__ residual,     // [M,N] or null
    void* __restrict__ Cout,                // [M,N] fp32 or bf16
    int M, int N, int K, int act, int outBf16)
{
    int bx, by;
    swizzle_bxy(bx, by);
    const int tid  = threadIdx.x;
    const int wv   = tid >> 6;
    const int lane = tid & 63;
    const int ln15 = lane & 15;
    const int lq   = lane >> 4;
    const int wm   = (wv >> 1) * 64;
    const int wn   = (wv & 1) * 64;
    const int row0 = by * 128;
    const int col0 = bx * 128;

    f32x4 acc[4][4];
    gemm_pipeline_core(A, Bt, K, row0, col0, wm, wn, ln15, lq, acc);

#pragma unroll
    for (int mi = 0; mi < 4; ++mi) {
#pragma unroll
        for (int ni = 0; ni < 4; ++ni) {
            const int gc = col0 + wn + ni * 16 + ln15;
            const float bv = bias[gc];
#pragma unroll
            for (int r = 0; r < 4; ++r) {
                const int gr = row0 + wm + mi * 16 + lq * 4 + r;
                float v = acc[mi][ni][r] + bv;
                if (act == 1) v = gelu_exact(v);
                if (residual) v += residual[(size_t)gr * N + gc];
                if (outBf16)
                    ((__hip_bfloat16*)Cout)[(size_t)gr * N + gc] = __float2bfloat16(v);
                else
                    ((float*)Cout)[(size_t)gr * N + gc] = v;
            }
        }
    }
}

// ---------------- 256x128 wide kernel (fc1)
__global__ __launch_bounds__(256, 2) void mfma_gemm_wide_kernel(
    const __hip_bfloat16* __restrict__ A,
    const __hip_bfloat16* __restrict__ Bt,
    const float* __restrict__ bias,
    void* __restrict__ Cout,
    int M, int N, int K, int act, int outBf16)
{
    int bx, by;
    swizzle_bxy(bx, by);
    const int tid  = threadIdx.x;
    const int wv   = tid >> 6;
    const int lane = tid & 63;
    const int ln15 = lane & 15;
    const int lq   = lane >> 4;
    const int wm   = (wv >> 1) * 128;
    const int wn   = (wv & 1) * 64;
    const int row0 = by * 256;
    const int col0 = bx * 128;

    f32x4 acc[8][4];
    gemm_pipeline_wide(A, Bt, K, row0, col0, wm, wn, ln15, lq, acc);

#pragma unroll
    for (int mi = 0; mi < 8; ++mi) {
#pragma unroll
        for (int ni = 0; ni < 4; ++ni) {
            const int gc = col0 + wn + ni * 16 + ln15;
            const float bv = bias[gc];
#pragma unroll
            for (int r = 0; r < 4; ++r) {
                const int gr = row0 + wm + mi * 16 + lq * 4 + r;
                float v = acc[mi][ni][r] + bv;
                if (act == 1) v = gelu_exact(v);
                if (outBf16)
                    ((__hip_bfloat16*)Cout)[(size_t)gr * N + gc] = __float2bfloat16(v);
                else
                    ((float*)Cout)[(size_t)gr * N + gc] = v;
            }
        }
    }
}

// ---------------- wide qkv kernel with routing epilogue
__global__ __launch_bounds__(256, 2) void mfma_qkv_kernel(
    const __hip_bfloat16* __restrict__ A,
    const __hip_bfloat16* __restrict__ Bt,
    const float* __restrict__ bias,
    __hip_bfloat16* __restrict__ Qb,
    __hip_bfloat16* __restrict__ Kb,
    __hip_bfloat16* __restrict__ Vtb)
{
    const int K = D_MODEL;
    int bx, by;
    swizzle_bxy(bx, by);
    const int tid  = threadIdx.x;
    const int wv   = tid >> 6;
    const int lane = tid & 63;
    const int ln15 = lane & 15;
    const int lq   = lane >> 4;
    const int wm   = (wv >> 1) * 128;
    const int wn   = (wv & 1) * 64;
    const int row0 = by * 256;
    const int col0 = bx * 128;

    f32x4 acc[8][4];
    gemm_pipeline_wide(A, Bt, K, row0, col0, wm, wn, ln15, lq, acc);

#pragma unroll
    for (int mi = 0; mi < 8; ++mi) {
        const int gr0 = row0 + wm + mi * 16 + lq * 4;   // + r
        const int bb  = gr0 >> 11;
        const int q0  = gr0 & 2047;
#pragma unroll
        for (int ni = 0; ni < 4; ++ni) {
            const int gc  = col0 + wn + ni * 16 + ln15;
            const float bv = bias[gc];
            const int sec = gc >> 10;            // 0:Q 1:K 2:V
            const int hd  = (gc & 1023) >> 6;
            const int d   = gc & 63;
            if (sec == 2) {
                unsigned short u[4];
#pragma unroll
                for (int r = 0; r < 4; ++r) {
                    __hip_bfloat16 e = __float2bfloat16(acc[mi][ni][r] + bv);
                    u[r] = *(unsigned short*)&e;
                }
                uint2 pk;
                pk.x = (unsigned int)u[0] | ((unsigned int)u[1] << 16);
                pk.y = (unsigned int)u[2] | ((unsigned int)u[3] << 16);
                *(uint2*)(Vtb + ((size_t)((bb * N_HEAD + hd) * D_HEAD + d)) * SEQ_T + q0) = pk;
            } else {
                __hip_bfloat16* dst = (sec == 0 ? Qb : Kb)
                    + ((size_t)((bb * N_HEAD + hd) * SEQ_T + q0)) * D_HEAD + d;
#pragma unroll
                for (int r = 0; r < 4; ++r)
                    dst[(size_t)r * D_HEAD] = __float2bfloat16(acc[mi][ni][r] + bv);
            }
        }
    }
}

// ------------------------------------------------- MFMA flash attention v3
// ATQ=64 q rows/block (16/wave), ATK=128. S^T via 16x16x32 (A=K,B=Q);
// PV via 16x16x16 with P直 from the S^T C-fragment (no LDS round-trip).
// K/V staged via register prefetch (global loads overlap compute).
#define ATQ 64
#define ATK 128
#define NQT (SEQ_T / ATQ)   // 32
#define KP  72              // Ks row stride (elems)
#define VP  136             // Vts row stride (elems)

__global__ __launch_bounds__(256) void mfma_attn_kernel(
    const __hip_bfloat16* __restrict__ Qb,
    const __hip_bfloat16* __restrict__ Kb,
    const __hip_bfloat16* __restrict__ Vtb,
    __hip_bfloat16* __restrict__ y)
{
    __shared__ __align__(16) __hip_bfloat16 Ks[ATK * KP];      // [j][d]; O-scratch in epilogue
    __shared__ __align__(16) __hip_bfloat16 Vts[D_HEAD * VP];  // [d][j]

    const int pair = blockIdx.x;   // 0..15
    const int h    = blockIdx.y;
    const int b    = blockIdx.z;
    const int tid  = threadIdx.x;
    const int wv   = tid >> 6;
    const int lane = tid & 63;
    const int ln15 = lane & 15;
    const int lq   = lane >> 4;

    const __hip_bfloat16* Qh = Qb  + (size_t)(b * N_HEAD + h) * SEQ_T * D_HEAD;
    const __hip_bfloat16* Kh = Kb  + (size_t)(b * N_HEAD + h) * SEQ_T * D_HEAD;
    const __hip_bfloat16* Vh = Vtb + (size_t)(b * N_HEAD + h) * D_HEAD * SEQ_T;
    const size_t bT = (size_t)b * SEQ_T;

    const float CEXP = 0.18033688011f;   // 0.125 * log2(e)

#pragma unroll 1
    for (int half = 0; half < 2; ++half) {
        const int qt    = half == 0 ? pair : (NQT - 1 - pair);
        const int qbase = qt * ATQ;
        const int ntk   = (qt >> 1) + 1;
        const int qg    = qbase + wv * 16 + ln15;   // stats-owner q row

        __syncthreads();   // protect restage vs prior half's epilogue reads

        bf16x8 qf[2];
#pragma unroll
        for (int kc = 0; kc < 2; ++kc)
            qf[kc] = *(const bf16x8*)(Qh + (size_t)(qbase + wv * 16 + ln15) * D_HEAD
                                      + kc * 32 + lq * 8);

        f32x4 Oacc[4];
#pragma unroll
        for (int dn = 0; dn < 4; ++dn) Oacc[dn] = (f32x4){0.f, 0.f, 0.f, 0.f};
        float m_run = -INFINITY, l_run = 0.f;

        uint4 kreg[4], vreg[4];
        auto load_tile = [&](int t) {
            const int kb = t * ATK;
#pragma unroll
            for (int i = 0; i < 4; ++i) {
                const int ch = tid + i * 256;
                const int kr = ch >> 3, kc8 = (ch & 7) * 8;
                kreg[i] = *(const uint4*)(Kh + (size_t)(kb + kr) * D_HEAD + kc8);
                const int vr = ch >> 4, vc8 = (ch & 15) * 8;
                vreg[i] = *(const uint4*)(Vh + (size_t)vr * SEQ_T + kb + vc8);
            }
        };
        auto write_tile = [&]() {
#pragma unroll
            for (int i = 0; i < 4; ++i) {
                const int ch = tid + i * 256;
                const int kr = ch >> 3, kc8 = (ch & 7) * 8;
                *(uint4*)&Ks[kr * KP + kc8] = kreg[i];
                const int vr = ch >> 4, vc8 = (ch & 15) * 8;
                *(uint4*)&Vts[vr * VP + vc8] = vreg[i];
            }
        };

        // prologue: tile 0 into LDS
        load_tile(0);
        write_tile();
        __syncthreads();

        for (int t = 0; t < ntk; ++t) {
            const int kb = t * ATK;
            if (t + 1 < ntk) load_tile(t + 1);   // overlap with compute

            // ---- S^T[j=128][q=16] : A=K (rows j), B=Q (rows q), 16x16x32
            f32x4 st[8];
#pragma unroll
            for (int jf = 0; jf < 8; ++jf) st[jf] = (f32x4){0.f, 0.f, 0.f, 0.f};
#pragma unroll
            for (int jf = 0; jf < 8; ++jf) {
                const bf16x8 kf0 = *(const bf16x8*)&Ks[(jf * 16 + ln15) * KP + lq * 8];
                const bf16x8 kf1 = *(const bf16x8*)&Ks[(jf * 16 + ln15) * KP + 32 + lq * 8];
                st[jf] = __builtin_amdgcn_mfma_f32_16x16x32_bf16(kf0, qf[0], st[jf], 0, 0, 0);
                st[jf] = __builtin_amdgcn_mfma_f32_16x16x32_bf16(kf1, qf[1], st[jf], 0, 0, 0);
            }

            // ---- causal mask on the diagonal tile (raw-score domain)
            if (t == ntk - 1) {
#pragma unroll
                for (int jf = 0; jf < 8; ++jf)
#pragma unroll
                    for (int r = 0; r < 4; ++r)
                        if ((kb + jf * 16 + lq * 4 + r) > qg) st[jf][r] = -INFINITY;
            }

            // ---- online softmax for q=qg (raw max; exp2 with folded scale)
            float tmax = st[0][0];
#pragma unroll
            for (int jf = 0; jf < 8; ++jf)
#pragma unroll
                for (int r = 0; r < 4; ++r) tmax = fmaxf(tmax, st[jf][r]);
            tmax = fmaxf(tmax, __shfl_xor(tmax, 16));
            tmax = fmaxf(tmax, __shfl_xor(tmax, 32));
            const float mnew  = fmaxf(m_run, tmax);
            const float alpha = exp2f((m_run - mnew) * CEXP);
            const float mc    = mnew * CEXP;
            float psum = 0.f;
#pragma unroll
            for (int jf = 0; jf < 8; ++jf)
#pragma unroll
                for (int r = 0; r < 4; ++r) {
                    const float p = exp2f(fmaf(st[jf][r], CEXP, -mc));
                    st[jf][r] = p;
                    psum += p;
                }
            psum += __shfl_xor(psum, 16);
            psum += __shfl_xor(psum, 32);
            l_run = alpha * l_run + psum;
            m_run = mnew;

            float a4[4];
#pragma unroll
            for (int r = 0; r < 4; ++r) a4[r] = __shfl(alpha, lq * 4 + r);
#pragma unroll
            for (int dn = 0; dn < 4; ++dn)
#pragma unroll
                for (int r = 0; r < 4; ++r) Oacc[dn][r] *= a4[r];

            // ---- O += P V via 16x16x16: P-frag is the S^T C-fragment
            // (lane: m=q=ln15, k=j=lq*4+r within jf) — no LDS round-trip.
#pragma unroll
            for (int jf = 0; jf < 8; ++jf) {
                s16x4 pfr;
#pragma unroll
                for (int s = 0; s < 4; ++s) {
                    __hip_bfloat16 e = __float2bfloat16(st[jf][s]);
                    pfr[s] = __builtin_bit_cast(short, e);
                }
#pragma unroll
                for (int dn = 0; dn < 4; ++dn) {
                    const s16x4 vfr = *(const s16x4*)&Vts[(dn * 16 + ln15) * VP
                                                          + jf * 16 + lq * 4];
                    Oacc[dn] = mfma16_bf16(pfr, vfr, Oacc[dn]);
                }
            }

            __syncthreads();                 // all waves done reading Ks/Vts
            if (t + 1 < ntk) {
                write_tile();                // regs (landed during compute) -> LDS
                __syncthreads();
            }
        }

        // ---- epilogue: transpose O through Ks (wave-private rows, stride 72)
        float il[4];
#pragma unroll
        for (int r = 0; r < 4; ++r) il[r] = 1.0f / __shfl(l_run, lq * 4 + r);
#pragma unroll
        for (int dn = 0; dn < 4; ++dn)
#pragma unroll
            for (int r = 0; r < 4; ++r)
                Ks[(wv * 16 + lq * 4 + r) * 72 + dn * 16 + ln15] =
                    __float2bfloat16(Oacc[dn][r] * il[r]);
        const int r2 = lane >> 3, c8 = (lane & 7) * 8;
#pragma unroll
        for (int i = 0; i < 2; ++i) {
            const int row = wv * 16 + r2 + 8 * i;
            const bf16x8 val = *(const bf16x8*)&Ks[row * 72 + c8];
            *(bf16x8*)(y + (bT + qbase + row) * D_MODEL + h * D_HEAD + c8) = val;
        }
    }
}

// ------------------------------------------------------------------ launch
extern "C" void kernel_launch(void* const* d_in, const int* in_sizes, int n_in,
                              void* d_out, int out_size, void* d_ws, size_t ws_size,
                              hipStream_t stream)
{
    const float* x      = (const float*)d_in[0];
    const float* ln1_w  = (const float*)d_in[1];
    const float* ln1_b  = (const float*)d_in[2];
    const float* attn_w = (const float*)d_in[3];
    const float* attn_b = (const float*)d_in[4];
    const float* proj_w = (const float*)d_in[5];
    const float* proj_b = (const float*)d_in[6];
    const float* ln2_w  = (const float*)d_in[7];
    const float* ln2_b  = (const float*)d_in[8];
    const float* fc_w   = (const float*)d_in[9];
    const float* fc_b   = (const float*)d_in[10];
    const float* fc2_w  = (const float*)d_in[11];
    const float* fc2_b  = (const float*)d_in[12];
    float* out = (float*)d_out;

    char* ws = (char*)d_ws;
    __hip_bfloat16* Qb      = (__hip_bfloat16*)(ws);
    __hip_bfloat16* Kb      = (__hip_bfloat16*)(ws + (size_t)8  * 1024 * 1024);
    __hip_bfloat16* Vtb     = (__hip_bfloat16*)(ws + (size_t)16 * 1024 * 1024);
    __hip_bfloat16* h_bf    = (__hip_bfloat16*)(ws);
    __hip_bfloat16* ln_buf  = (__hip_bfloat16*)(ws + (size_t)32 * 1024 * 1024);
    __hip_bfloat16* y_buf   = (__hip_bfloat16*)(ws + (size_t)40 * 1024 * 1024);
    float*          xmid    = (float*)(ws + (size_t)48 * 1024 * 1024);
    __hip_bfloat16* attn_wt = (__hip_bfloat16*)(ws + (size_t)64 * 1024 * 1024);
    __hip_bfloat16* proj_wt = (__hip_bfloat16*)(ws + (size_t)70 * 1024 * 1024);
    __hip_bfloat16* fc_wt   = (__hip_bfloat16*)(ws + (size_t)72 * 1024 * 1024);
    __hip_bfloat16* fc2_wt  = (__hip_bfloat16*)(ws + (size_t)80 * 1024 * 1024);

    dim3 blk256(256);

    // 0. all weight transposes in one launch (fp32 [K,N] -> bf16 [N,K])
    transpose_all_kernel<<<dim3(12288), blk256, 0, stream>>>(
        attn_w, proj_w, fc_w, fc2_w, attn_wt, proj_wt, fc_wt, fc2_wt);

    // 1. ln1(x) -> ln_buf (bf16)
    ln_kernel<<<dim3(NROWS), blk256, 0, stream>>>(x, ln1_w, ln1_b, ln_buf, D_MODEL);

    // 2. qkv GEMM (wide 256x128) -> Qb/Kb/Vtb
    mfma_qkv_kernel<<<dim3(C3 / 128, NROWS / 256), blk256, 0, stream>>>(
        ln_buf, attn_wt, attn_b, Qb, Kb, Vtb);

    // 3. MFMA flash attention v3 -> y_buf (bf16)
    mfma_attn_kernel<<<dim3(NQT / 2, N_HEAD, BATCH), blk256, 0, stream>>>(
        Qb, Kb, Vtb, y_buf);

    // 4. xmid = x + y_buf @ proj_w + proj_b  (fp32, 128x128 kernel)
    mfma_gemm_kernel<<<dim3(D_MODEL / 128, NROWS / 128), blk256, 0, stream>>>(
        y_buf, proj_wt, proj_b, x, xmid, NROWS, D_MODEL, D_MODEL, 0, 0);

    // 5. ln2(xmid) -> ln_buf (bf16)
    ln_kernel<<<dim3(NROWS), blk256, 0, stream>>>(xmid, ln2_w, ln2_b, ln_buf, D_MODEL);

    // 6. h = gelu(ln_buf @ fc_w + fc_b) -> bf16 (wide 256x128)
    mfma_gemm_wide_kernel<<<dim3(D_FF / 128, NROWS / 256), blk256, 0, stream>>>(
        ln_buf, fc_wt, fc_b, h_bf, NROWS, D_FF, D_MODEL, 1, 1);

    // 7. out = xmid + h @ fc2_w + fc2_b  (fp32, 128x128 kernel)
    mfma_gemm_kernel<<<dim3(D_MODEL / 128, NROWS / 128), blk256, 0, stream>>>(
        h_bf, fc2_wt, fc2_b, xmid, out, NROWS, D_MODEL, D_FF, 0, 0);
}

// Round 11
// 414.523 us; speedup vs baseline: 1.0848x; 1.0848x over previous
//
#include <hip/hip_runtime.h>
#include <hip/hip_bf16.h>
#include <math.h>

// Transformer block. Round 11: attention v4 — direct global->LDS staging
// (Round 9 style; Round 10's register prefetch spilled to scratch: 260MB
// WRITE_SIZE) + keep v3's wins: PV via 16x16x16 from the S^T C-fragment
// (no P LDS round-trip), exp2-folded softmax, 36KB LDS. GEMMs as Round 9.
// D_MODEL=1024, N_HEAD=16, D_HEAD=64, EXP=4, B=2, T=2048, EPS=1e-5

#define D_MODEL 1024
#define N_HEAD  16
#define D_HEAD  64
#define SEQ_T   2048
#define BATCH   2
#define NROWS   (BATCH * SEQ_T)   // 4096
#define C3      (3 * D_MODEL)     // 3072
#define D_FF    (4 * D_MODEL)     // 4096

typedef __bf16 bf16x8 __attribute__((ext_vector_type(8)));
typedef __bf16 bf16x4t __attribute__((ext_vector_type(4)));
typedef short  s16x4  __attribute__((ext_vector_type(4)));
typedef float  f32x4  __attribute__((ext_vector_type(4)));

// s_waitcnt imm: vmcnt[3:0]=bits3:0, expcnt=bits6:4, lgkmcnt=bits11:8.
#define WAIT_VM6() __builtin_amdgcn_s_waitcnt(0x0F76)
#define WAIT_VM4() __builtin_amdgcn_s_waitcnt(0x0F74)
#define WAIT_VM0() __builtin_amdgcn_s_waitcnt(0x0F70)

// 16x16x16 bf16 MFMA: builtin name differs across ROCm versions.
__device__ __forceinline__ f32x4 mfma16_bf16(s16x4 a, s16x4 b, f32x4 c)
{
#if __has_builtin(__builtin_amdgcn_mfma_f32_16x16x16_bf16)
    return __builtin_amdgcn_mfma_f32_16x16x16_bf16(
        __builtin_bit_cast(bf16x4t, a), __builtin_bit_cast(bf16x4t, b), c, 0, 0, 0);
#else
    return __builtin_amdgcn_mfma_f32_16x16x16bf16_1k(a, b, c, 0, 0, 0);
#endif
}

// ---------------------------------------------------------------- LayerNorm
__global__ __launch_bounds__(256) void ln_kernel(
    const float* __restrict__ in, const float* __restrict__ w,
    const float* __restrict__ b, __hip_bfloat16* __restrict__ out, int D)
{
    const int row = blockIdx.x;
    const int tid = threadIdx.x;
    const float* x = in + (size_t)row * D;

    float s = 0.f, s2 = 0.f;
    for (int i = tid; i < D; i += 256) {
        float v = x[i];
        s += v; s2 += v * v;
    }
    __shared__ float rs[256], rs2[256];
    rs[tid] = s; rs2[tid] = s2;
    __syncthreads();
    for (int off = 128; off > 0; off >>= 1) {
        if (tid < off) { rs[tid] += rs[tid + off]; rs2[tid] += rs2[tid + off]; }
        __syncthreads();
    }
    const float mu   = rs[0] / D;
    const float var  = rs2[0] / D - mu * mu;
    const float rstd = rsqrtf(var + 1e-5f);

    __hip_bfloat16* o = out + (size_t)row * D;
    for (int i = tid; i < D; i += 256)
        o[i] = __float2bfloat16((x[i] - mu) * rstd * w[i] + b[i]);
}

// -------------------------------- merged weight transpose + bf16 cast (x4)
__global__ __launch_bounds__(256) void transpose_all_kernel(
    const float* __restrict__ attn_w, const float* __restrict__ proj_w,
    const float* __restrict__ fc_w,   const float* __restrict__ fc2_w,
    __hip_bfloat16* __restrict__ attn_wt, __hip_bfloat16* __restrict__ proj_wt,
    __hip_bfloat16* __restrict__ fc_wt,   __hip_bfloat16* __restrict__ fc2_wt)
{
    __shared__ float t[32][33];
    int tb = blockIdx.x;
    const float* W; __hip_bfloat16* Wt; int K, N;
    if (tb < 3072)      { W = attn_w; Wt = attn_wt; K = D_MODEL; N = C3; }
    else if (tb < 4096) { tb -= 3072; W = proj_w; Wt = proj_wt; K = D_MODEL; N = D_MODEL; }
    else if (tb < 8192) { tb -= 4096; W = fc_w;   Wt = fc_wt;   K = D_MODEL; N = D_FF; }
    else                { tb -= 8192; W = fc2_w;  Wt = fc2_wt;  K = D_FF;    N = D_MODEL; }
    const int ntx = N >> 5;
    const int k0 = (tb / ntx) * 32;
    const int n0 = (tb % ntx) * 32;

    const int tx = threadIdx.x & 31;
    const int ty = threadIdx.x >> 5;
#pragma unroll
    for (int i = 0; i < 4; ++i)
        t[ty + 8 * i][tx] = W[(size_t)(k0 + ty + 8 * i) * N + n0 + tx];
    __syncthreads();
#pragma unroll
    for (int i = 0; i < 4; ++i)
        Wt[(size_t)(n0 + ty + 8 * i) * K + k0 + tx] =
            __float2bfloat16(t[tx][ty + 8 * i]);
}

// ----------------------------------------------------------- helpers
__device__ __forceinline__ void async16(const __hip_bfloat16* g, __hip_bfloat16* l)
{
    __builtin_amdgcn_global_load_lds(
        (const __attribute__((address_space(1))) void*)g,
        (__attribute__((address_space(3))) void*)l, 16, 0, 0);
}

__device__ __forceinline__ float gelu_exact(float v)
{
    return 0.5f * v * (1.0f + erff(v * 0.70710678118654752f));
}

__device__ __forceinline__ void swizzle_bxy(int& bx, int& by)
{
    const int nbx = gridDim.x;
    const int lin = blockIdx.y * nbx + blockIdx.x;
    const int stripe = 4 * nbx;
    const int s = lin / stripe;
    const int rem = lin - s * stripe;
    by = s * 4 + (rem & 3);
    bx = rem >> 2;
}

// ---------------- Round-8 core: 128x128 block, 64x64 wave, 4-deep, vmcnt(4)
__device__ __forceinline__ void gemm_pipeline_core(
    const __hip_bfloat16* __restrict__ A,
    const __hip_bfloat16* __restrict__ Bt,
    int K, int row0, int col0,
    int wm, int wn, int ln15, int lq,
    f32x4 (&acc)[4][4])
{
    __shared__ __align__(16) __hip_bfloat16 As0[4096], As1[4096],
                                            As2[4096], As3[4096];
    __shared__ __align__(16) __hip_bfloat16 Bs0[4096], Bs1[4096],
                                            Bs2[4096], Bs3[4096];
    __hip_bfloat16* const Ab[4] = {As0, As1, As2, As3};
    __hip_bfloat16* const Bb[4] = {Bs0, Bs1, Bs2, Bs3};

    const int tid  = threadIdx.x;
    const int wv   = tid >> 6;
    const int lane = tid & 63;
    const int sr = wv * 16 + (lane >> 2);
    const int sq = (lane & 3) * 8;

    auto stage = [&](int kt, __hip_bfloat16* as, __hip_bfloat16* bs) {
        const int k0 = kt * 32;
#pragma unroll
        for (int i = 0; i < 2; ++i) {
            const int r = i * 64 + sr;
            async16(A  + (size_t)(row0 + r) * K + k0 + sq, as + r * 32);
            async16(Bt + (size_t)(col0 + r) * K + k0 + sq, bs + r * 32);
        }
    };

#pragma unroll
    for (int i = 0; i < 4; ++i)
#pragma unroll
        for (int j = 0; j < 4; ++j) acc[i][j] = (f32x4){0.f, 0.f, 0.f, 0.f};

    stage(0, Ab[0], Bb[0]);
    stage(1, Ab[1], Bb[1]);

    const int nt = K >> 5;
    for (int t0 = 0; t0 < nt; t0 += 4) {
#pragma unroll
        for (int u = 0; u < 4; ++u) {
            const int t = t0 + u;
            if (t + 1 < nt) WAIT_VM4(); else WAIT_VM0();
            __builtin_amdgcn_s_barrier();
            const __hip_bfloat16* as = Ab[u];
            const __hip_bfloat16* bs = Bb[u];
            bf16x8 af[4], bfr[4];
#pragma unroll
            for (int mi = 0; mi < 4; ++mi)
                af[mi] = *(const bf16x8*)&as[(wm + mi * 16 + ln15) * 32 + lq * 8];
#pragma unroll
            for (int ni = 0; ni < 4; ++ni)
                bfr[ni] = *(const bf16x8*)&bs[(wn + ni * 16 + ln15) * 32 + lq * 8];
#pragma unroll
            for (int mi = 0; mi < 4; ++mi)
#pragma unroll
                for (int ni = 0; ni < 4; ++ni)
                    acc[mi][ni] = __builtin_amdgcn_mfma_f32_16x16x32_bf16(
                        af[mi], bfr[ni], acc[mi][ni], 0, 0, 0);
            if (t + 2 < nt) stage(t + 2, Ab[(u + 2) & 3], Bb[(u + 2) & 3]);
        }
    }
}

// ---------------- Round-9 wide core: 256x128 block, 128x64 wave, 2-deep
__device__ __forceinline__ void gemm_pipeline_wide(
    const __hip_bfloat16* __restrict__ A,
    const __hip_bfloat16* __restrict__ Bt,
    int K, int row0, int col0,
    int wm, int wn, int ln15, int lq,
    f32x4 (&acc)[8][4])
{
    __shared__ __align__(16) __hip_bfloat16 As0[256 * 32], As1[256 * 32];
    __shared__ __align__(16) __hip_bfloat16 Bs0[128 * 32], Bs1[128 * 32];

    const int tid  = threadIdx.x;
    const int wv   = tid >> 6;
    const int lane = tid & 63;
    const int sr = wv * 16 + (lane >> 2);
    const int sq = (lane & 3) * 8;

    auto stage = [&](int kt, __hip_bfloat16* as, __hip_bfloat16* bs) {
        const int k0 = kt * 32;
#pragma unroll
        for (int i = 0; i < 4; ++i) {
            const int r = i * 64 + sr;
            async16(A + (size_t)(row0 + r) * K + k0 + sq, as + r * 32);
        }
#pragma unroll
        for (int i = 0; i < 2; ++i) {
            const int r = i * 64 + sr;
            async16(Bt + (size_t)(col0 + r) * K + k0 + sq, bs + r * 32);
        }
    };

#pragma unroll
    for (int i = 0; i < 8; ++i)
#pragma unroll
        for (int j = 0; j < 4; ++j) acc[i][j] = (f32x4){0.f, 0.f, 0.f, 0.f};

    stage(0, As0, Bs0);
    stage(1, As1, Bs1);

    const int nt = K >> 5;
    for (int t0 = 0; t0 < nt; t0 += 2) {
#pragma unroll
        for (int u = 0; u < 2; ++u) {
            const int t = t0 + u;
            if (t + 1 < nt) WAIT_VM6(); else WAIT_VM0();
            __builtin_amdgcn_s_barrier();
            const __hip_bfloat16* as = u ? As1 : As0;
            const __hip_bfloat16* bs = u ? Bs1 : Bs0;
            bf16x8 af[8], bfr[4];
#pragma unroll
            for (int mi = 0; mi < 8; ++mi)
                af[mi] = *(const bf16x8*)&as[(wm + mi * 16 + ln15) * 32 + lq * 8];
#pragma unroll
            for (int ni = 0; ni < 4; ++ni)
                bfr[ni] = *(const bf16x8*)&bs[(wn + ni * 16 + ln15) * 32 + lq * 8];
#pragma unroll
            for (int mi = 0; mi < 8; ++mi)
#pragma unroll
                for (int ni = 0; ni < 4; ++ni)
                    acc[mi][ni] = __builtin_amdgcn_mfma_f32_16x16x32_bf16(
                        af[mi], bfr[ni], acc[mi][ni], 0, 0, 0);
            __builtin_amdgcn_s_barrier();
            if (t + 2 < nt) stage(t + 2, u ? As1 : As0, u ? Bs1 : Bs0);
        }
    }
}

// ---------------- 128x128 kernel (proj, fc2)
__global__ __launch_bounds__(256) void mfma_gemm_kernel(
    const __hip_bfloat16* __restrict__ A,   // [M,K]
    const __hip_bfloat16* __restrict__ Bt,  // [N,K]
    const float* __restrict__ bias,         // [N]
    const float* __restrict__ residual,     // [M,N] or null
    void* __restrict__ Cout,                // [M,N] fp32 or bf16
    int M, int N, int K, int act, int outBf16)
{
    int bx, by;
    swizzle_bxy(bx, by);
    const int tid  = threadIdx.x;
    const int wv   = tid >> 6;
    const int lane = tid & 63;
    const int ln15 = lane & 15;
    const int lq   = lane >> 4;
    const int wm   = (wv >> 1) * 64;
    const int wn   = (wv & 1) * 64;
    const int row0 = by * 128;
    const int col0 = bx * 128;

    f32x4 acc[4][4];
    gemm_pipeline_core(A, Bt, K, row0, col0, wm, wn, ln15, lq, acc);

#pragma unroll
    for (int mi = 0; mi < 4; ++mi) {
#pragma unroll
        for (int ni = 0; ni < 4; ++ni) {
            const int gc = col0 + wn + ni * 16 + ln15;
            const float bv = bias[gc];
#pragma unroll
            for (int r = 0; r < 4; ++r) {
                const int gr = row0 + wm + mi * 16 + lq * 4 + r;
                float v = acc[mi][ni][r] + bv;
                if (act == 1) v = gelu_exact(v);
                if (residual) v += residual[(size_t)gr * N + gc];
                if (outBf16)
                    ((__hip_bfloat16*)Cout)[(size_t)gr * N + gc] = __float2bfloat16(v);
                else
                    ((float*)Cout)[(size_t)gr * N + gc] = v;
            }
        }
    }
}

// ---------------- 256x128 wide kernel (fc1)
__global__ __launch_bounds__(256, 2) void mfma_gemm_wide_kernel(
    const __hip_bfloat16* __restrict__ A,
    const __hip_bfloat16* __restrict__ Bt,
    const float* __restrict__ bias,
    void* __restrict__ Cout,
    int M, int N, int K, int act, int outBf16)
{
    int bx, by;
    swizzle_bxy(bx, by);
    const int tid  = threadIdx.x;
    const int wv   = tid >> 6;
    const int lane = tid & 63;
    const int ln15 = lane & 15;
    const int lq   = lane >> 4;
    const int wm   = (wv >> 1) * 128;
    const int wn   = (wv & 1) * 64;
    const int row0 = by * 256;
    const int col0 = bx * 128;

    f32x4 acc[8][4];
    gemm_pipeline_wide(A, Bt, K, row0, col0, wm, wn, ln15, lq, acc);

#pragma unroll
    for (int mi = 0; mi < 8; ++mi) {
#pragma unroll
        for (int ni = 0; ni < 4; ++ni) {
            const int gc = col0 + wn + ni * 16 + ln15;
            const float bv = bias[gc];
#pragma unroll
            for (int r = 0; r < 4; ++r) {
                const int gr = row0 + wm + mi * 16 + lq * 4 + r;
                float v = acc[mi][ni][r] + bv;
                if (act == 1) v = gelu_exact(v);
                if (outBf16)
                    ((__hip_bfloat16*)Cout)[(size_t)gr * N + gc] = __float2bfloat16(v);
                else
                    ((float*)Cout)[(size_t)gr * N + gc] = v;
            }
        }
    }
}

// ---------------- wide qkv kernel with routing epilogue
__global__ __launch_bounds__(256, 2) void mfma_qkv_kernel(
    const __hip_bfloat16* __restrict__ A,
    const __hip_bfloat16* __restrict__ Bt,
    const float* __restrict__ bias,
    __hip_bfloat16* __restrict__ Qb,
    __hip_bfloat16* __restrict__ Kb,
    __hip_bfloat16* __restrict__ Vtb)
{
    const int K = D_MODEL;
    int bx, by;
    swizzle_bxy(bx, by);
    const int tid  = threadIdx.x;
    const int wv   = tid >> 6;
    const int lane = tid & 63;
    const int ln15 = lane & 15;
    const int lq   = lane >> 4;
    const int wm   = (wv >> 1) * 128;
    const int wn   = (wv & 1) * 64;
    const int row0 = by * 256;
    const int col0 = bx * 128;

    f32x4 acc[8][4];
    gemm_pipeline_wide(A, Bt, K, row0, col0, wm, wn, ln15, lq, acc);

#pragma unroll
    for (int mi = 0; mi < 8; ++mi) {
        const int gr0 = row0 + wm + mi * 16 + lq * 4;   // + r
        const int bb  = gr0 >> 11;
        const int q0  = gr0 & 2047;
#pragma unroll
        for (int ni = 0; ni < 4; ++ni) {
            const int gc  = col0 + wn + ni * 16 + ln15;
            const float bv = bias[gc];
            const int sec = gc >> 10;            // 0:Q 1:K 2:V
            const int hd  = (gc & 1023) >> 6;
            const int d   = gc & 63;
            if (sec == 2) {
                unsigned short u[4];
#pragma unroll
                for (int r = 0; r < 4; ++r) {
                    __hip_bfloat16 e = __float2bfloat16(acc[mi][ni][r] + bv);
                    u[r] = *(unsigned short*)&e;
                }
                uint2 pk;
                pk.x = (unsigned int)u[0] | ((unsigned int)u[1] << 16);
                pk.y = (unsigned int)u[2] | ((unsigned int)u[3] << 16);
                *(uint2*)(Vtb + ((size_t)((bb * N_HEAD + hd) * D_HEAD + d)) * SEQ_T + q0) = pk;
            } else {
                __hip_bfloat16* dst = (sec == 0 ? Qb : Kb)
                    + ((size_t)((bb * N_HEAD + hd) * SEQ_T + q0)) * D_HEAD + d;
#pragma unroll
                for (int r = 0; r < 4; ++r)
                    dst[(size_t)r * D_HEAD] = __float2bfloat16(acc[mi][ni][r] + bv);
            }
        }
    }
}

// ------------------------------------------------- MFMA flash attention v4
// ATQ=64 q rows/block (16/wave), ATK=128. S^T via 16x16x32 (A=K,B=Q);
// PV via 16x16x16 with P straight from the S^T C-fragment (no LDS trip).
// Direct global->LDS staging (R9 style); 36KB LDS -> 4 blocks/CU.
#define ATQ 64
#define ATK 128
#define NQT (SEQ_T / ATQ)   // 32
#define KP  72              // Ks row stride (elems)
#define VP  136             // Vts row stride (elems)

__global__ __launch_bounds__(256) void mfma_attn_kernel(
    const __hip_bfloat16* __restrict__ Qb,
    const __hip_bfloat16* __restrict__ Kb,
    const __hip_bfloat16* __restrict__ Vtb,
    __hip_bfloat16* __restrict__ y)
{
    __shared__ __align__(16) __hip_bfloat16 Ks[ATK * KP];      // [j][d]; O-scratch in epilogue
    __shared__ __align__(16) __hip_bfloat16 Vts[D_HEAD * VP];  // [d][j]

    const int pair = blockIdx.x;   // 0..15
    const int h    = blockIdx.y;
    const int b    = blockIdx.z;
    const int tid  = threadIdx.x;
    const int wv   = tid >> 6;
    const int lane = tid & 63;
    const int ln15 = lane & 15;
    const int lq   = lane >> 4;

    const __hip_bfloat16* Qh = Qb  + (size_t)(b * N_HEAD + h) * SEQ_T * D_HEAD;
    const __hip_bfloat16* Kh = Kb  + (size_t)(b * N_HEAD + h) * SEQ_T * D_HEAD;
    const __hip_bfloat16* Vh = Vtb + (size_t)(b * N_HEAD + h) * D_HEAD * SEQ_T;
    const size_t bT = (size_t)b * SEQ_T;

    const float CEXP = 0.18033688011f;   // 0.125 * log2(e)

#pragma unroll 1
    for (int half = 0; half < 2; ++half) {
        const int qt    = half == 0 ? pair : (NQT - 1 - pair);
        const int qbase = qt * ATQ;
        const int ntk   = (qt >> 1) + 1;
        const int qg    = qbase + wv * 16 + ln15;   // stats-owner q row

        bf16x8 qf[2];
#pragma unroll
        for (int kc = 0; kc < 2; ++kc)
            qf[kc] = *(const bf16x8*)(Qh + (size_t)(qbase + wv * 16 + ln15) * D_HEAD
                                      + kc * 32 + lq * 8);

        f32x4 Oacc[4];
#pragma unroll
        for (int dn = 0; dn < 4; ++dn) Oacc[dn] = (f32x4){0.f, 0.f, 0.f, 0.f};
        float m_run = -INFINITY, l_run = 0.f;

        for (int t = 0; t < ntk; ++t) {
            const int kb = t * ATK;
            __syncthreads();   // prev iter's LDS reads (and prev-half epilogue) done
            // stage K tile [128][64]
#pragma unroll
            for (int i = 0; i < 4; ++i) {
                const int ch = tid + i * 256;
                const int r = ch >> 3, c8 = (ch & 7) * 8;
                *(bf16x8*)&Ks[r * KP + c8] =
                    *(const bf16x8*)(Kh + (size_t)(kb + r) * D_HEAD + c8);
            }
            // stage Vt tile [64][128]
#pragma unroll
            for (int i = 0; i < 4; ++i) {
                const int ch = tid + i * 256;
                const int r = ch >> 4, c8 = (ch & 15) * 8;
                *(bf16x8*)&Vts[r * VP + c8] =
                    *(const bf16x8*)(Vh + (size_t)r * SEQ_T + kb + c8);
            }
            __syncthreads();

            // ---- S^T[j=128][q=16] : A=K (rows j), B=Q (rows q), 16x16x32
            f32x4 st[8];
#pragma unroll
            for (int jf = 0; jf < 8; ++jf) st[jf] = (f32x4){0.f, 0.f, 0.f, 0.f};
#pragma unroll
            for (int jf = 0; jf < 8; ++jf) {
                const bf16x8 kf0 = *(const bf16x8*)&Ks[(jf * 16 + ln15) * KP + lq * 8];
                const bf16x8 kf1 = *(const bf16x8*)&Ks[(jf * 16 + ln15) * KP + 32 + lq * 8];
                st[jf] = __builtin_amdgcn_mfma_f32_16x16x32_bf16(kf0, qf[0], st[jf], 0, 0, 0);
                st[jf] = __builtin_amdgcn_mfma_f32_16x16x32_bf16(kf1, qf[1], st[jf], 0, 0, 0);
            }

            // ---- causal mask on the diagonal tile (raw-score domain)
            if (t == ntk - 1) {
#pragma unroll
                for (int jf = 0; jf < 8; ++jf)
#pragma unroll
                    for (int r = 0; r < 4; ++r)
                        if ((kb + jf * 16 + lq * 4 + r) > qg) st[jf][r] = -INFINITY;
            }

            // ---- online softmax for q=qg (raw max; exp2 with folded scale)
            float tmax = st[0][0];
#pragma unroll
            for (int jf = 0; jf < 8; ++jf)
#pragma unroll
                for (int r = 0; r < 4; ++r) tmax = fmaxf(tmax, st[jf][r]);
            tmax = fmaxf(tmax, __shfl_xor(tmax, 16));
            tmax = fmaxf(tmax, __shfl_xor(tmax, 32));
            const float mnew  = fmaxf(m_run, tmax);
            const float alpha = exp2f((m_run - mnew) * CEXP);
            const float mc    = mnew * CEXP;
            float psum = 0.f;
#pragma unroll
            for (int jf = 0; jf < 8; ++jf)
#pragma unroll
                for (int r = 0; r < 4; ++r) {
                    const float p = exp2f(fmaf(st[jf][r], CEXP, -mc));
                    st[jf][r] = p;
                    psum += p;
                }
            psum += __shfl_xor(psum, 16);
            psum += __shfl_xor(psum, 32);
            l_run = alpha * l_run + psum;
            m_run = mnew;

            float a4[4];
#pragma unroll
            for (int r = 0; r < 4; ++r) a4[r] = __shfl(alpha, lq * 4 + r);
#pragma unroll
            for (int dn = 0; dn < 4; ++dn)
#pragma unroll
                for (int r = 0; r < 4; ++r) Oacc[dn][r] *= a4[r];

            // ---- O += P V via 16x16x16: P-frag is the S^T C-fragment
            // (lane: m=q=ln15, k=j=lq*4+r within jf) — no LDS round-trip.
#pragma unroll
            for (int jf = 0; jf < 8; ++jf) {
                s16x4 pfr;
#pragma unroll
                for (int s = 0; s < 4; ++s) {
                    __hip_bfloat16 e = __float2bfloat16(st[jf][s]);
                    pfr[s] = __builtin_bit_cast(short, e);
                }
#pragma unroll
                for (int dn = 0; dn < 4; ++dn) {
                    const s16x4 vfr = *(const s16x4*)&Vts[(dn * 16 + ln15) * VP
                                                          + jf * 16 + lq * 4];
                    Oacc[dn] = mfma16_bf16(pfr, vfr, Oacc[dn]);
                }
            }
        }

        // ---- epilogue: transpose O through Ks (barrier: Ks reuse after reads)
        __syncthreads();
        float il[4];
#pragma unroll
        for (int r = 0; r < 4; ++r) il[r] = 1.0f / __shfl(l_run, lq * 4 + r);
#pragma unroll
        for (int dn = 0; dn < 4; ++dn)
#pragma unroll
            for (int r = 0; r < 4; ++r)
                Ks[(wv * 16 + lq * 4 + r) * 72 + dn * 16 + ln15] =
                    __float2bfloat16(Oacc[dn][r] * il[r]);
        const int r2 = lane >> 3, c8 = (lane & 7) * 8;
#pragma unroll
        for (int i = 0; i < 2; ++i) {
            const int row = wv * 16 + r2 + 8 * i;
            const bf16x8 val = *(const bf16x8*)&Ks[row * 72 + c8];
            *(bf16x8*)(y + (bT + qbase + row) * D_MODEL + h * D_HEAD + c8) = val;
        }
    }
}

// ------------------------------------------------------------------ launch
extern "C" void kernel_launch(void* const* d_in, const int* in_sizes, int n_in,
                              void* d_out, int out_size, void* d_ws, size_t ws_size,
                              hipStream_t stream)
{
    const float* x      = (const float*)d_in[0];
    const float* ln1_w  = (const float*)d_in[1];
    const float* ln1_b  = (const float*)d_in[2];
    const float* attn_w = (const float*)d_in[3];
    const float* attn_b = (const float*)d_in[4];
    const float* proj_w = (const float*)d_in[5];
    const float* proj_b = (const float*)d_in[6];
    const float* ln2_w  = (const float*)d_in[7];
    const float* ln2_b  = (const float*)d_in[8];
    const float* fc_w   = (const float*)d_in[9];
    const float* fc_b   = (const float*)d_in[10];
    const float* fc2_w  = (const float*)d_in[11];
    const float* fc2_b  = (const float*)d_in[12];
    float* out = (float*)d_out;

    char* ws = (char*)d_ws;
    __hip_bfloat16* Qb      = (__hip_bfloat16*)(ws);
    __hip_bfloat16* Kb      = (__hip_bfloat16*)(ws + (size_t)8  * 1024 * 1024);
    __hip_bfloat16* Vtb     = (__hip_bfloat16*)(ws + (size_t)16 * 1024 * 1024);
    __hip_bfloat16* h_bf    = (__hip_bfloat16*)(ws);
    __hip_bfloat16* ln_buf  = (__hip_bfloat16*)(ws + (size_t)32 * 1024 * 1024);
    __hip_bfloat16* y_buf   = (__hip_bfloat16*)(ws + (size_t)40 * 1024 * 1024);
    float*          xmid    = (float*)(ws + (size_t)48 * 1024 * 1024);
    __hip_bfloat16* attn_wt = (__hip_bfloat16*)(ws + (size_t)64 * 1024 * 1024);
    __hip_bfloat16* proj_wt = (__hip_bfloat16*)(ws + (size_t)70 * 1024 * 1024);
    __hip_bfloat16* fc_wt   = (__hip_bfloat16*)(ws + (size_t)72 * 1024 * 1024);
    __hip_bfloat16* fc2_wt  = (__hip_bfloat16*)(ws + (size_t)80 * 1024 * 1024);

    dim3 blk256(256);

    // 0. all weight transposes in one launch (fp32 [K,N] -> bf16 [N,K])
    transpose_all_kernel<<<dim3(12288), blk256, 0, stream>>>(
        attn_w, proj_w, fc_w, fc2_w, attn_wt, proj_wt, fc_wt, fc2_wt);

    // 1. ln1(x) -> ln_buf (bf16)
    ln_kernel<<<dim3(NROWS), blk256, 0, stream>>>(x, ln1_w, ln1_b, ln_buf, D_MODEL);

    // 2. qkv GEMM (wide 256x128) -> Qb/Kb/Vtb
    mfma_qkv_kernel<<<dim3(C3 / 128, NROWS / 256), blk256, 0, stream>>>(
        ln_buf, attn_wt, attn_b, Qb, Kb, Vtb);

    // 3. MFMA flash attention v4 -> y_buf (bf16)
    mfma_attn_kernel<<<dim3(NQT / 2, N_HEAD, BATCH), blk256, 0, stream>>>(
        Qb, Kb, Vtb, y_buf);

    // 4. xmid = x + y_buf @ proj_w + proj_b  (fp32, 128x128 kernel)
    mfma_gemm_kernel<<<dim3(D_MODEL / 128, NROWS / 128), blk256, 0, stream>>>(
        y_buf, proj_wt, proj_b, x, xmid, NROWS, D_MODEL, D_MODEL, 0, 0);

    // 5. ln2(xmid) -> ln_buf (bf16)
    ln_kernel<<<dim3(NROWS), blk256, 0, stream>>>(xmid, ln2_w, ln2_b, ln_buf, D_MODEL);

    // 6. h = gelu(ln_buf @ fc_w + fc_b) -> bf16 (wide 256x128)
    mfma_gemm_wide_kernel<<<dim3(D_FF / 128, NROWS / 256), blk256, 0, stream>>>(
        ln_buf, fc_wt, fc_b, h_bf, NROWS, D_FF, D_MODEL, 1, 1);

    // 7. out = xmid + h @ fc2_w + fc2_b  (fp32, 128x128 kernel)
    mfma_gemm_kernel<<<dim3(D_MODEL / 128, NROWS / 128), blk256, 0, stream>>>(
        h_bf, fc2_wt, fc2_b, xmid, out, NROWS, D_MODEL, D_FF, 0, 0);
}